// Round 10
// baseline (554.963 us; speedup 1.0000x reference)
//
#include <hip/hip_runtime.h>

#define F 128
#define NEG_SLOPE 0.01f
#define NPB 512      // nodes per bucket (1<<9)
#define PMAX 256     // max buckets; nP = ceil(N/512) = 196
#define HB 8192      // edges per hist block
#define BB 8192      // edges per bin block
#define CAP 12288    // csr LDS staging capacity (avg 8192 + tail; key-0 << this)

typedef _Float16 half8_t __attribute__((ext_vector_type(8)));
typedef float f32x4 __attribute__((ext_vector_type(4)));

// ---------------- CSR build: two-level bucket sort (r5 structure) ----------------
// Edge records pack to 4B: (dst_local<<17)|src -- dst_local<512 (9b), src<2^17.

__global__ __launch_bounds__(512) void zero_bcnt(int* __restrict__ bcnt,
                                                 int* __restrict__ bcur) {
    int tid = threadIdx.x;
    if (tid < PMAX) bcnt[tid] = 0;
    else bcur[tid - PMAX] = 0;
}

// hist over dst buckets; last 32 blocks instead convert W1/W2 to fp16.
__global__ __launch_bounds__(256) void hist_kernel(const int* __restrict__ dst,
                                                   int* __restrict__ bcnt,
                                                   int E, int nP,
                                                   const float* __restrict__ W1,
                                                   const float* __restrict__ W2,
                                                   _Float16* __restrict__ W1h,
                                                   _Float16* __restrict__ W2h) {
    __shared__ int h[PMAX];
    int tid = threadIdx.x;
    int hb = gridDim.x - 32;
    if (blockIdx.x >= hb) {
        int i = (blockIdx.x - hb) * 256 + tid;    // 0 .. 8191 (2 * 128*128/4)
        const int n4 = F * F / 4;
        const float* in = (i < n4) ? W1 : W2;
        _Float16* out = (i < n4) ? W1h : W2h;
        int j = (i < n4) ? i : i - n4;
        float4 v = ((const float4*)in)[j];
        half8_t hx;  // only low 4 used
        hx[0] = (_Float16)v.x; hx[1] = (_Float16)v.y;
        hx[2] = (_Float16)v.z; hx[3] = (_Float16)v.w;
        *(int2*)&((_Float16*)out)[j * 4] = *(int2*)&hx;
        return;
    }
    if (tid < PMAX) h[tid] = 0;
    __syncthreads();
    int base = blockIdx.x * HB;
    for (int i = tid; i < HB && base + i < E; i += 256)
        atomicAdd(&h[dst[base + i] >> 9], 1);
    __syncthreads();
    if (tid < nP && h[tid]) atomicAdd(&bcnt[tid], h[tid]);
}

// bin: per-block bucket hist + local scan + in-block global scan of bcnt
// + LDS reorder + coalesced run writes.
__global__ __launch_bounds__(256) void bin_kernel(const int* __restrict__ src,
                                                  const int* __restrict__ dst,
                                                  const int* __restrict__ bcnt,
                                                  int* __restrict__ bcur,
                                                  int* __restrict__ bbase,
                                                  int* __restrict__ binned,
                                                  int E, int nP) {
    __shared__ int hist[PMAX];
    __shared__ int lbase[PMAX];
    __shared__ int gbase[PMAX];
    __shared__ int cur[PMAX];
    __shared__ int sa[PMAX];
    __shared__ int sb[PMAX];
    __shared__ int buf[BB];
    __shared__ unsigned char b8[BB];
    int tid = threadIdx.x;
    int base = blockIdx.x * BB;
    int myE = E - base; if (myE > BB) myE = BB;

    hist[tid] = 0;
    __syncthreads();
    for (int i = tid; i < myE; i += 256)
        atomicAdd(&hist[dst[base + i] >> 9], 1);
    __syncthreads();
    // scan A: local hist -> lbase/cur
    {
        int v = (tid < nP) ? hist[tid] : 0;
        int run = v;
        sa[tid] = v;
        __syncthreads();
        for (int off = 1; off < PMAX; off <<= 1) {
            int add = (tid >= off) ? sa[tid - off] : 0;
            __syncthreads();
            run += add;
            sa[tid] = run;
            __syncthreads();
        }
        if (tid < nP) { lbase[tid] = run - v; cur[tid] = run - v; }
    }
    // scan B: global bcnt -> exclusive prefix; alloc via bcur atomics
    {
        int v = (tid < nP) ? bcnt[tid] : 0;
        int run = v;
        sb[tid] = v;
        __syncthreads();
        for (int off = 1; off < PMAX; off <<= 1) {
            int add = (tid >= off) ? sb[tid - off] : 0;
            __syncthreads();
            run += add;
            sb[tid] = run;
            __syncthreads();
        }
        int gexc = run - v;
        if (tid < nP) {
            if (blockIdx.x == 0) bbase[tid] = gexc;
            gbase[tid] = hist[tid] ? gexc + atomicAdd(&bcur[tid], hist[tid]) : 0;
        }
    }
    __syncthreads();
    // reorder into LDS, bucket-contiguous
    for (int i = tid; i < myE; i += 256) {
        int d = dst[base + i], s = src[base + i];
        int b = d >> 9;
        int lp = atomicAdd(&cur[b], 1);
        buf[lp] = ((d & (NPB - 1)) << 17) | s;
        b8[lp] = (unsigned char)b;
    }
    __syncthreads();
    // coalesced run writes
    for (int j = tid; j < myE; j += 256) {
        int b = b8[j];
        binned[gbase[b] + (j - lbase[b])] = buf[j];
    }
}

// one block per bucket (196 blocks): exact CSR + offs + dis
__global__ __launch_bounds__(256) void csr_kernel(const int* __restrict__ binned,
                                                  const int* __restrict__ bcnt,
                                                  const int* __restrict__ bbase,
                                                  int* __restrict__ srcs,
                                                  int* __restrict__ offs,
                                                  float* __restrict__ dis, int N) {
    __shared__ int cnt[NPB];
    __shared__ int tmp[NPB];
    __shared__ int cur[NPB];
    __shared__ int buf[CAP];
    int tid = threadIdx.x;
    int b = blockIdx.x;
    int ebase = bbase[b];
    int count = bcnt[b];
    int lo = b << 9;
    cnt[tid] = 0;
    cnt[tid + 256] = 0;
    __syncthreads();
    for (int j = tid; j < count; j += 256)
        atomicAdd(&cnt[binned[ebase + j] >> 17], 1);
    __syncthreads();
    int j0 = tid, j1 = tid + 256;
    int v0 = cnt[j0], v1 = cnt[j1];
    tmp[j0] = v0; tmp[j1] = v1;
    __syncthreads();
    for (int off = 1; off < NPB; off <<= 1) {
        int t0 = tmp[j0] + (j0 >= off ? tmp[j0 - off] : 0);
        int t1 = tmp[j1] + (j1 >= off ? tmp[j1 - off] : 0);
        __syncthreads();
        tmp[j0] = t0; tmp[j1] = t1;
        __syncthreads();
    }
    int e0 = tmp[j0] - v0, e1 = tmp[j1] - v1;
    cur[j0] = e0; cur[j1] = e1;
    int n0 = lo + j0, n1 = lo + j1;
    if (n0 < N) { offs[n0] = ebase + e0; dis[n0] = rsqrtf((float)v0 + 1.0f); }
    if (n1 < N) { offs[n1] = ebase + e1; dis[n1] = rsqrtf((float)v1 + 1.0f); }
    __syncthreads();
    for (int j = tid; j < count; j += 256) {
        int rec = binned[ebase + j];
        int pos = atomicAdd(&cur[rec >> 17], 1);
        int s = rec & 0x1FFFF;
        if (pos < CAP) buf[pos] = s; else srcs[ebase + pos] = s;
    }
    __syncthreads();
    int lim = count < CAP ? count : CAP;
    for (int j = tid; j < lim; j += 256)
        srcs[ebase + j] = buf[j];
}

// ---------------- GEMM layer 1: hhS = slice-major[(x @ W1.T) * dis] ----------------
// Output is SLICE-MAJOR: 8 contiguous sub-tables of 16 features x N nodes
// (hhS[t*SL + node*16 + m], SL = ntiles*256 fp16). Slice t is a contiguous
// 3.2MB region -> fits one XCD's 4MB L2 for the downstream sliced gather,
// and cache lines never straddle slices.

__global__ __launch_bounds__(256) void gemm_a32(const float* __restrict__ A,
                                                const _Float16* __restrict__ Wh,
                                                const float* __restrict__ dis,
                                                _Float16* __restrict__ out,
                                                int ntiles) {
    int wave = threadIdx.x >> 6;
    int lane = threadIdx.x & 63;
    int tile = blockIdx.x * 4 + wave;
    if (tile >= ntiles) return;
    int m = lane & 15, quad = lane >> 4;
    const float* arow = A + (size_t)tile * 16 * F;
    half8_t afrag[4];
#pragma unroll
    for (int c = 0; c < 4; ++c) {
        float4 t0 = *(const float4*)&arow[m * F + c * 32 + quad * 8];
        float4 t1 = *(const float4*)&arow[m * F + c * 32 + quad * 8 + 4];
        afrag[c][0] = (_Float16)t0.x; afrag[c][1] = (_Float16)t0.y;
        afrag[c][2] = (_Float16)t0.z; afrag[c][3] = (_Float16)t0.w;
        afrag[c][4] = (_Float16)t1.x; afrag[c][5] = (_Float16)t1.y;
        afrag[c][6] = (_Float16)t1.z; afrag[c][7] = (_Float16)t1.w;
    }
    f32x4 acc[8];
#pragma unroll
    for (int t = 0; t < 8; ++t) acc[t] = (f32x4){0.f, 0.f, 0.f, 0.f};
#pragma unroll
    for (int c = 0; c < 4; ++c) {
#pragma unroll
        for (int t = 0; t < 8; ++t) {
            half8_t bfrag = *(const half8_t*)&Wh[(t * 16 + m) * F + c * 32 + quad * 8];
            acc[t] = __builtin_amdgcn_mfma_f32_16x16x32_f16(afrag[c], bfrag, acc[t],
                                                            0, 0, 0);
        }
    }
    float d[4];
#pragma unroll
    for (int r = 0; r < 4; ++r) d[r] = dis[tile * 16 + quad * 4 + r];
    size_t SL = (size_t)ntiles * 256;
#pragma unroll
    for (int t = 0; t < 8; ++t)
#pragma unroll
        for (int r = 0; r < 4; ++r) {
            int node = tile * 16 + quad * 4 + r;
            out[(size_t)t * SL + (size_t)node * 16 + m] = (_Float16)(acc[t][r] * d[r]);
        }
}

// ---------------- GEMM layer 2: slice-major in AND out ----------------
// A-fragment feature f = c*32+quad*8+j -> slice fs = c*2+(quad>>1),
// offset (quad&1)*8 (8 | 16 so a half8 never crosses a slice).

__global__ __launch_bounds__(256) void gemm_a16(const _Float16* __restrict__ A,
                                                const _Float16* __restrict__ Wh,
                                                const float* __restrict__ dis,
                                                _Float16* __restrict__ out,
                                                int ntiles) {
    int wave = threadIdx.x >> 6;
    int lane = threadIdx.x & 63;
    int tile = blockIdx.x * 4 + wave;
    if (tile >= ntiles) return;
    int m = lane & 15, quad = lane >> 4;
    size_t SL = (size_t)ntiles * 256;
    half8_t afrag[4];
#pragma unroll
    for (int c = 0; c < 4; ++c) {
        int fs = c * 2 + (quad >> 1);
        int off = (quad & 1) * 8;
        afrag[c] = *(const half8_t*)
            &A[(size_t)fs * SL + (size_t)(tile * 16 + m) * 16 + off];
    }
    f32x4 acc[8];
#pragma unroll
    for (int t = 0; t < 8; ++t) acc[t] = (f32x4){0.f, 0.f, 0.f, 0.f};
#pragma unroll
    for (int c = 0; c < 4; ++c) {
#pragma unroll
        for (int t = 0; t < 8; ++t) {
            half8_t bfrag = *(const half8_t*)&Wh[(t * 16 + m) * F + c * 32 + quad * 8];
            acc[t] = __builtin_amdgcn_mfma_f32_16x16x32_f16(afrag[c], bfrag, acc[t],
                                                            0, 0, 0);
        }
    }
    float d[4];
#pragma unroll
    for (int r = 0; r < 4; ++r) d[r] = dis[tile * 16 + quad * 4 + r];
#pragma unroll
    for (int t = 0; t < 8; ++t)
#pragma unroll
        for (int r = 0; r < 4; ++r) {
            int node = tile * 16 + quad * 4 + r;
            out[(size_t)t * SL + (size_t)node * 16 + m] = (_Float16)(acc[t][r] * d[r]);
        }
}

// ---------------- feature-sliced, XCD-affine aggregation ----------------
// fs = blockIdx % 8: round-robin block->XCD dispatch parks slice fs's
// 3.2MB sub-table in XCD fs's 4MB L2 -> row gather misses drop from
// ~178MB (first-touch over the whole 25.6MB table per XCD) to ~25.6MB
// (first touch of each slice once, then L2-hot). srcs is streamed
// nontemporally so the 8x re-read cannot evict the row slice.
// Wave = 2 nodes x 16 edge slots x 2 half-rows (16B each). Reduce over
// slot bits (xor 2/4/8/16) keeps node halves and 16B halves separate.
// Epilogue identical math to before, restricted to this slice's 16 feats.

#define AGS_BODY(TBL)                                                          \
    int fs = blockIdx.x & 7;                                                   \
    int ng = blockIdx.x >> 3;                                                  \
    int w = threadIdx.x >> 6;                                                  \
    int lane = threadIdx.x & 63;                                               \
    int slot = (lane >> 1) & 15;                                               \
    int h = lane & 1;                                                          \
    int node = ng * 8 + w * 2 + (lane >> 5);                                   \
    if (node >= n) return;                                                     \
    const half8_t* Ts = TBL + (size_t)fs * sl8;                                \
    int beg = offs[node];                                                      \
    int end = (node + 1 < n) ? offs[node + 1] : E;                             \
    float di = dis[node];                                                      \
    half8_t hv = Ts[(size_t)node * 2 + h];                                     \
    float4 bb = ((const float4*)bias)[fs * 4 + h * 2];                         \
    float4 bb2 = ((const float4*)bias)[fs * 4 + h * 2 + 1];                    \
    float acc[8];                                                              \
    _Pragma("unroll") for (int j = 0; j < 8; ++j) acc[j] = 0.f;                \
    for (int e = beg; e < end; e += 16) {                                      \
        int idx = e + slot;                                                    \
        int s = __builtin_nontemporal_load(&srcs[idx < end ? idx : beg]);      \
        float wv = (idx < end) ? 1.f : 0.f;                                    \
        half8_t a = Ts[(size_t)s * 2 + h];                                     \
        _Pragma("unroll") for (int j = 0; j < 8; ++j)                          \
            acc[j] += wv * (float)a[j];                                        \
    }                                                                          \
    _Pragma("unroll") for (int j = 0; j < 8; ++j) {                            \
        acc[j] += __shfl_xor(acc[j], 2);                                       \
        acc[j] += __shfl_xor(acc[j], 4);                                       \
        acc[j] += __shfl_xor(acc[j], 8);                                       \
        acc[j] += __shfl_xor(acc[j], 16);                                      \
    }                                                                          \
    if (slot != 0) return;                                                     \
    acc[0] = di * (acc[0] + (float)hv[0]) + bb.x;                              \
    acc[1] = di * (acc[1] + (float)hv[1]) + bb.y;                              \
    acc[2] = di * (acc[2] + (float)hv[2]) + bb.z;                              \
    acc[3] = di * (acc[3] + (float)hv[3]) + bb.w;                              \
    acc[4] = di * (acc[4] + (float)hv[4]) + bb2.x;                             \
    acc[5] = di * (acc[5] + (float)hv[5]) + bb2.y;                             \
    acc[6] = di * (acc[6] + (float)hv[6]) + bb2.z;                             \
    acc[7] = di * (acc[7] + (float)hv[7]) + bb2.w;                             \
    _Pragma("unroll") for (int j = 0; j < 8; ++j)                              \
        acc[j] = (acc[j] > 0.f) ? acc[j] : acc[j] * NEG_SLOPE;

__global__ __launch_bounds__(256) void agg_h_slice(const half8_t* __restrict__ tbl,
                                                   const float* __restrict__ dis,
                                                   const float* __restrict__ bias,
                                                   const int* __restrict__ srcs,
                                                   const int* __restrict__ offs,
                                                   half8_t* __restrict__ gout,
                                                   int n, int E, int sl8) {
    AGS_BODY(tbl)
    half8_t o;
#pragma unroll
    for (int j = 0; j < 8; ++j) o[j] = (_Float16)acc[j];
    gout[(size_t)fs * sl8 + (size_t)node * 2 + h] = o;
}

__global__ __launch_bounds__(256) void agg_f_slice(const half8_t* __restrict__ tbl,
                                                   const float* __restrict__ dis,
                                                   const float* __restrict__ bias,
                                                   const int* __restrict__ srcs,
                                                   const int* __restrict__ offs,
                                                   float* __restrict__ out,
                                                   int n, int E, int sl8) {
    AGS_BODY(tbl)
    float* op = out + (size_t)node * F + fs * 16 + h * 8;
    *(float4*)op = make_float4(acc[0], acc[1], acc[2], acc[3]);
    *(float4*)(op + 4) = make_float4(acc[4], acc[5], acc[6], acc[7]);
}

// ---------------- launch ----------------

static inline size_t alup(size_t x) { return (x + 255) & ~(size_t)255; }

extern "C" void kernel_launch(void* const* d_in, const int* in_sizes, int n_in,
                              void* d_out, int out_size, void* d_ws, size_t ws_size,
                              hipStream_t stream) {
    const float* x  = (const float*)d_in[0];
    const int*   ei = (const int*)d_in[1];
    const float* W1 = (const float*)d_in[2];
    const float* b1 = (const float*)d_in[3];
    const float* W2 = (const float*)d_in[4];
    const float* b2 = (const float*)d_in[5];
    float* out = (float*)d_out;

    const int N = in_sizes[0] / F;    // 100000  (< 2^17 for 4B packing)
    const int E = in_sizes[1] / 2;    // 1600000
    const int* src = ei;
    const int* dst = ei + E;

    const int ntiles = (N + 15) / 16;          // 6250
    const size_t tblsz = (size_t)ntiles * 16 * F * 2;  // slice-major fp16 table

    char* p = (char*)d_ws;
    int*      bcnt   = (int*)p;      p += alup(PMAX * 4);
    int*      bbase  = (int*)p;      p += alup(PMAX * 4);
    int*      bcur   = (int*)p;      p += alup(PMAX * 4);
    float*    dis    = (float*)p;    p += alup((size_t)N * 4);
    int*      offs   = (int*)p;      p += alup((size_t)N * 4);
    int*      binned = (int*)p;      p += alup((size_t)E * 4);
    int*      srcs   = (int*)p;      p += alup((size_t)E * 4);
    _Float16* gS     = (_Float16*)p; p += alup(tblsz);
    _Float16* hhS    = (_Float16*)p; p += alup(tblsz);
    _Float16* W1h    = (_Float16*)p; p += alup((size_t)F * F * 2);
    _Float16* W2h    = (_Float16*)p; p += alup((size_t)F * F * 2);

    const int nP = (N + NPB - 1) / NPB;        // 196
    const int gemm_grid = (ntiles + 3) / 4;
    const int agg_grid = ((N + 7) / 8) * 8;    // 8 nodes/block x 8 slices
    const int sl8 = ntiles * 32;               // half8 units per slice

    zero_bcnt<<<1, 512, 0, stream>>>(bcnt, bcur);
    hist_kernel<<<(E + HB - 1) / HB + 32, 256, 0, stream>>>(dst, bcnt, E, nP,
                                                            W1, W2, W1h, W2h);
    bin_kernel<<<(E + BB - 1) / BB, 256, 0, stream>>>(src, dst, bcnt, bcur,
                                                      bbase, binned, E, nP);
    csr_kernel<<<nP, 256, 0, stream>>>(binned, bcnt, bbase, srcs, offs, dis, N);

    // layer 1 GEMM: hhS = slice-major[(x @ W1.T)*dis]
    gemm_a32<<<gemm_grid, 256, 0, stream>>>(x, W1h, dis, hhS, ntiles);
    // layer 1 agg (sliced, XCD-affine): gS = slice-major[agg(hhS)+b1+lrelu]
    agg_h_slice<<<agg_grid, 256, 0, stream>>>((const half8_t*)hhS, dis, b1,
                                              srcs, offs, (half8_t*)gS, N, E, sl8);
    // layer 2 GEMM: hhS = slice-major[(g @ W2.T)*dis]   (reuses hhS)
    gemm_a16<<<gemm_grid, 256, 0, stream>>>(gS, W2h, dis, hhS, ntiles);
    // layer 2 agg (sliced): out = agg(hhS)+b2+lrelu (fp32 row-major)
    agg_f_slice<<<agg_grid, 256, 0, stream>>>((const half8_t*)hhS, dis, b2,
                                              srcs, offs, out, N, E, sl8);
}

// Round 12
// 327.416 us; speedup vs baseline: 1.6950x; 1.6950x over previous
//
#include <hip/hip_runtime.h>

#define F 128
#define NEG_SLOPE 0.01f
#define NPB 512      // nodes per bucket (1<<9)
#define PMAX 256     // max buckets; nP = ceil(N/512) = 196
#define HB 8192      // edges per hist block
#define BB 8192      // edges per bin block
#define CAP 12288    // csr LDS staging capacity (avg 8192 + tail; key-0 << this)

typedef _Float16 half8_t __attribute__((ext_vector_type(8)));
typedef _Float16 half4_t __attribute__((ext_vector_type(4)));
typedef float f32x4 __attribute__((ext_vector_type(4)));

// v_fma_mix_f32: acc(f32) += f16half(reg) * one -- single-instruction
// convert+FMA, numerically identical to (float)h * 1.0f + acc.
#define MIX_ACC(j, reg, sel)                                                   \
    asm("v_fma_mix_f32 %0, %1, %2, %0 op_sel:[" sel ",0,0] op_sel_hi:[1,0,0]"  \
        : "+v"(acc[j]) : "v"(reg), "v"(one));
#define MIX_ROW(a)                                                             \
    MIX_ACC(0, a.x, "0") MIX_ACC(1, a.x, "1")                                  \
    MIX_ACC(2, a.y, "0") MIX_ACC(3, a.y, "1")                                  \
    MIX_ACC(4, a.z, "0") MIX_ACC(5, a.z, "1")                                  \
    MIX_ACC(6, a.w, "0") MIX_ACC(7, a.w, "1")

// ---------------- CSR build: two-level bucket sort (r5 structure) ----------------
// Edge records pack to 4B: (dst_local<<17)|src -- dst_local<512 (9b), src<2^17.

__global__ __launch_bounds__(512) void zero_bcnt(int* __restrict__ bcnt,
                                                 int* __restrict__ bcur) {
    int tid = threadIdx.x;
    if (tid < PMAX) bcnt[tid] = 0;
    else bcur[tid - PMAX] = 0;
}

// hist over dst buckets; last 32 blocks instead convert W1/W2 to fp16.
// Block hb additionally zeroes the PAD ROW (row N) of both gather tables:
// out-of-range edge slots gather this zero row instead of carrying masks.
__global__ __launch_bounds__(256) void hist_kernel(const int* __restrict__ dst,
                                                   int* __restrict__ bcnt,
                                                   int E, int nP,
                                                   const float* __restrict__ W1,
                                                   const float* __restrict__ W2,
                                                   _Float16* __restrict__ W1h,
                                                   _Float16* __restrict__ W2h,
                                                   _Float16* __restrict__ hpad,
                                                   _Float16* __restrict__ gpad) {
    __shared__ int h[PMAX];
    int tid = threadIdx.x;
    int hb = gridDim.x - 32;
    if (blockIdx.x >= hb) {
        if (blockIdx.x == hb) {
            if (tid < 64) ((int*)hpad)[tid] = 0;
            else if (tid < 128) ((int*)gpad)[tid - 64] = 0;
        }
        int i = (blockIdx.x - hb) * 256 + tid;    // 0 .. 8191 (2 * 128*128/4)
        const int n4 = F * F / 4;
        const float* in = (i < n4) ? W1 : W2;
        _Float16* out = (i < n4) ? W1h : W2h;
        int j = (i < n4) ? i : i - n4;
        float4 v = ((const float4*)in)[j];
        half8_t hx;  // only low 4 used
        hx[0] = (_Float16)v.x; hx[1] = (_Float16)v.y;
        hx[2] = (_Float16)v.z; hx[3] = (_Float16)v.w;
        *(int2*)&((_Float16*)out)[j * 4] = *(int2*)&hx;
        return;
    }
    if (tid < PMAX) h[tid] = 0;
    __syncthreads();
    int base = blockIdx.x * HB;
    for (int i = tid; i < HB && base + i < E; i += 256)
        atomicAdd(&h[dst[base + i] >> 9], 1);
    __syncthreads();
    if (tid < nP && h[tid]) atomicAdd(&bcnt[tid], h[tid]);
}

// bin: per-block bucket hist + local scan + in-block global scan of bcnt
// + LDS reorder + coalesced run writes.
__global__ __launch_bounds__(256) void bin_kernel(const int* __restrict__ src,
                                                  const int* __restrict__ dst,
                                                  const int* __restrict__ bcnt,
                                                  int* __restrict__ bcur,
                                                  int* __restrict__ bbase,
                                                  int* __restrict__ binned,
                                                  int E, int nP) {
    __shared__ int hist[PMAX];
    __shared__ int lbase[PMAX];
    __shared__ int gbase[PMAX];
    __shared__ int cur[PMAX];
    __shared__ int sa[PMAX];
    __shared__ int sb[PMAX];
    __shared__ int buf[BB];
    __shared__ unsigned char b8[BB];
    int tid = threadIdx.x;
    int base = blockIdx.x * BB;
    int myE = E - base; if (myE > BB) myE = BB;

    hist[tid] = 0;
    __syncthreads();
    for (int i = tid; i < myE; i += 256)
        atomicAdd(&hist[dst[base + i] >> 9], 1);
    __syncthreads();
    // scan A: local hist -> lbase/cur
    {
        int v = (tid < nP) ? hist[tid] : 0;
        int run = v;
        sa[tid] = v;
        __syncthreads();
        for (int off = 1; off < PMAX; off <<= 1) {
            int add = (tid >= off) ? sa[tid - off] : 0;
            __syncthreads();
            run += add;
            sa[tid] = run;
            __syncthreads();
        }
        if (tid < nP) { lbase[tid] = run - v; cur[tid] = run - v; }
    }
    // scan B: global bcnt -> exclusive prefix; alloc via bcur atomics
    {
        int v = (tid < nP) ? bcnt[tid] : 0;
        int run = v;
        sb[tid] = v;
        __syncthreads();
        for (int off = 1; off < PMAX; off <<= 1) {
            int add = (tid >= off) ? sb[tid - off] : 0;
            __syncthreads();
            run += add;
            sb[tid] = run;
            __syncthreads();
        }
        int gexc = run - v;
        if (tid < nP) {
            if (blockIdx.x == 0) bbase[tid] = gexc;
            gbase[tid] = hist[tid] ? gexc + atomicAdd(&bcur[tid], hist[tid]) : 0;
        }
    }
    __syncthreads();
    // reorder into LDS, bucket-contiguous
    for (int i = tid; i < myE; i += 256) {
        int d = dst[base + i], s = src[base + i];
        int b = d >> 9;
        int lp = atomicAdd(&cur[b], 1);
        buf[lp] = ((d & (NPB - 1)) << 17) | s;
        b8[lp] = (unsigned char)b;
    }
    __syncthreads();
    // coalesced run writes
    for (int j = tid; j < myE; j += 256) {
        int b = b8[j];
        binned[gbase[b] + (j - lbase[b])] = buf[j];
    }
}

// one block per bucket (196 blocks): exact CSR + offs + dis
__global__ __launch_bounds__(256) void csr_kernel(const int* __restrict__ binned,
                                                  const int* __restrict__ bcnt,
                                                  const int* __restrict__ bbase,
                                                  int* __restrict__ srcs,
                                                  int* __restrict__ offs,
                                                  float* __restrict__ dis, int N) {
    __shared__ int cnt[NPB];
    __shared__ int tmp[NPB];
    __shared__ int cur[NPB];
    __shared__ int buf[CAP];
    int tid = threadIdx.x;
    int b = blockIdx.x;
    int ebase = bbase[b];
    int count = bcnt[b];
    int lo = b << 9;
    cnt[tid] = 0;
    cnt[tid + 256] = 0;
    __syncthreads();
    for (int j = tid; j < count; j += 256)
        atomicAdd(&cnt[binned[ebase + j] >> 17], 1);
    __syncthreads();
    int j0 = tid, j1 = tid + 256;
    int v0 = cnt[j0], v1 = cnt[j1];
    tmp[j0] = v0; tmp[j1] = v1;
    __syncthreads();
    for (int off = 1; off < NPB; off <<= 1) {
        int t0 = tmp[j0] + (j0 >= off ? tmp[j0 - off] : 0);
        int t1 = tmp[j1] + (j1 >= off ? tmp[j1 - off] : 0);
        __syncthreads();
        tmp[j0] = t0; tmp[j1] = t1;
        __syncthreads();
    }
    int e0 = tmp[j0] - v0, e1 = tmp[j1] - v1;
    cur[j0] = e0; cur[j1] = e1;
    int n0 = lo + j0, n1 = lo + j1;
    if (n0 < N) { offs[n0] = ebase + e0; dis[n0] = rsqrtf((float)v0 + 1.0f); }
    if (n1 < N) { offs[n1] = ebase + e1; dis[n1] = rsqrtf((float)v1 + 1.0f); }
    __syncthreads();
    for (int j = tid; j < count; j += 256) {
        int rec = binned[ebase + j];
        int pos = atomicAdd(&cur[rec >> 17], 1);
        int s = rec & 0x1FFFF;
        if (pos < CAP) buf[pos] = s; else srcs[ebase + pos] = s;
    }
    __syncthreads();
    int lim = count < CAP ? count : CAP;
    for (int j = tid; j < lim; j += 256)
        srcs[ebase + j] = buf[j];
}

// ---------------- GEMM layer 1: hh = (x @ W1.T) * dis[row] ----------------
// NOTE: writes rows [0, ntiles*16); with N = 100000 (multiple of 16) this
// never touches the pad row N.

__global__ __launch_bounds__(256) void gemm_a32(const float* __restrict__ A,
                                                const _Float16* __restrict__ Wh,
                                                const float* __restrict__ dis,
                                                _Float16* __restrict__ out,
                                                int ntiles) {
    int wave = threadIdx.x >> 6;
    int lane = threadIdx.x & 63;
    int tile = blockIdx.x * 4 + wave;
    if (tile >= ntiles) return;
    int m = lane & 15, quad = lane >> 4;
    const float* arow = A + (size_t)tile * 16 * F;
    half8_t afrag[4];
#pragma unroll
    for (int c = 0; c < 4; ++c) {
        float4 t0 = *(const float4*)&arow[m * F + c * 32 + quad * 8];
        float4 t1 = *(const float4*)&arow[m * F + c * 32 + quad * 8 + 4];
        afrag[c][0] = (_Float16)t0.x; afrag[c][1] = (_Float16)t0.y;
        afrag[c][2] = (_Float16)t0.z; afrag[c][3] = (_Float16)t0.w;
        afrag[c][4] = (_Float16)t1.x; afrag[c][5] = (_Float16)t1.y;
        afrag[c][6] = (_Float16)t1.z; afrag[c][7] = (_Float16)t1.w;
    }
    f32x4 acc[8];
#pragma unroll
    for (int t = 0; t < 8; ++t) acc[t] = (f32x4){0.f, 0.f, 0.f, 0.f};
#pragma unroll
    for (int c = 0; c < 4; ++c) {
#pragma unroll
        for (int t = 0; t < 8; ++t) {
            half8_t bfrag = *(const half8_t*)&Wh[(t * 16 + m) * F + c * 32 + quad * 8];
            acc[t] = __builtin_amdgcn_mfma_f32_16x16x32_f16(afrag[c], bfrag, acc[t],
                                                            0, 0, 0);
        }
    }
    float d[4];
#pragma unroll
    for (int r = 0; r < 4; ++r) d[r] = dis[tile * 16 + quad * 4 + r];
    _Float16* orow = out + (size_t)tile * 16 * F;
#pragma unroll
    for (int t = 0; t < 8; ++t)
#pragma unroll
        for (int r = 0; r < 4; ++r)
            orow[(quad * 4 + r) * F + t * 16 + m] = (_Float16)(acc[t][r] * d[r]);
}

// ---------------- FUSED layer-boundary: agg(layer1) + GEMM(W2) ----------------
// r9 structure (4 waves, swizzled LDS, transposed GEMM with 8B stores) with
// the gather inner loop rewritten: pad-row indexing (no edge masks) and
// v_fma_mix_f32 (1 inst per feature instead of cvt+fma).

__global__ __launch_bounds__(256) void agg_gemm16(const half8_t* __restrict__ h8,
                                                  const float* __restrict__ dis,
                                                  const float* __restrict__ bias,
                                                  const _Float16* __restrict__ Wh,
                                                  const int* __restrict__ srcs,
                                                  const int* __restrict__ offs,
                                                  _Float16* __restrict__ out,
                                                  int n, int E) {
    __shared__ _Float16 Af[16 * F];   // 4KB, XOR-swizzled 16B chunks
    int tile = blockIdx.x;
    int w = threadIdx.x >> 6;         // 0..3
    int lane = threadIdx.x & 63;
    int g = lane >> 4;
    int fo = lane & 15;
    float one = 1.0f;
    float4 b0 = ((const float4*)bias)[fo * 2];
    float4 b1v = ((const float4*)bias)[fo * 2 + 1];

#pragma unroll
    for (int i = 0; i < 4; ++i) {
        int row = w * 4 + i;
        int node = tile * 16 + row;
        float acc[8];
#pragma unroll
        for (int j = 0; j < 8; ++j) acc[j] = 0.f;
        int beg = 0, end = 0;
        float di = 0.f;
        half8_t hv = {};
        if (node < n) {
            beg = offs[node];
            end = (node + 1 < n) ? offs[node + 1] : E;
            di = dis[node];
            hv = h8[(size_t)node * 16 + fo];
        }
        if (beg < end) {
            int i0 = beg + g, i1 = beg + 4 + g;
            int s0 = (i0 < end) ? srcs[i0] : n;
            int s1 = (i1 < end) ? srcs[i1] : n;
            for (int e = beg; e < end; e += 8) {
                int ns0 = n, ns1 = n;
                if (e + 8 < end) {
                    int j0 = e + 8 + g, j1 = e + 12 + g;
                    ns0 = (j0 < end) ? srcs[j0] : n;
                    ns1 = (j1 < end) ? srcs[j1] : n;
                }
                int4 a0 = *(const int4*)&h8[(size_t)s0 * 16 + fo];
                int4 a1 = *(const int4*)&h8[(size_t)s1 * 16 + fo];
                MIX_ROW(a0)
                MIX_ROW(a1)
                s0 = ns0; s1 = ns1;
            }
        }
#pragma unroll
        for (int j = 0; j < 8; ++j) {
            acc[j] += __shfl_xor(acc[j], 16);
            acc[j] += __shfl_xor(acc[j], 32);
        }
        if (lane < 16) {
            half8_t o = {};
            if (node < n) {
                acc[0] = di * (acc[0] + (float)hv[0]) + b0.x;
                acc[1] = di * (acc[1] + (float)hv[1]) + b0.y;
                acc[2] = di * (acc[2] + (float)hv[2]) + b0.z;
                acc[3] = di * (acc[3] + (float)hv[3]) + b0.w;
                acc[4] = di * (acc[4] + (float)hv[4]) + b1v.x;
                acc[5] = di * (acc[5] + (float)hv[5]) + b1v.y;
                acc[6] = di * (acc[6] + (float)hv[6]) + b1v.z;
                acc[7] = di * (acc[7] + (float)hv[7]) + b1v.w;
#pragma unroll
                for (int j = 0; j < 8; ++j) {
                    float v = (acc[j] > 0.f) ? acc[j] : acc[j] * NEG_SLOPE;
                    o[j] = (_Float16)v;
                }
            }
            int cs = fo ^ (row & 7);                 // swizzled chunk
            *(half8_t*)&Af[row * F + cs * 8] = o;
        }
    }
    __syncthreads();

    // Transposed GEMM: A = W2 slice t (m=feature), B = Af (n=node).
    // D: col=lane&15=node, row=quad*4+r=feature-within-slice.
    int m = fo, quad = g;
    half8_t bfragA[4];
#pragma unroll
    for (int c = 0; c < 4; ++c)
        bfragA[c] = *(const half8_t*)&Af[fo * F + ((c * 4 + quad) ^ (fo & 7)) * 8];
    int onode = tile * 16 + fo;
    float di2 = (onode < n) ? dis[onode] : 0.f;
#pragma unroll
    for (int s = 0; s < 2; ++s) {
        int t = w * 2 + s;
        f32x4 acc2 = (f32x4){0.f, 0.f, 0.f, 0.f};
#pragma unroll
        for (int c = 0; c < 4; ++c) {
            half8_t afragW = *(const half8_t*)&Wh[(t * 16 + m) * F + c * 32 + quad * 8];
            acc2 = __builtin_amdgcn_mfma_f32_16x16x32_f16(afragW, bfragA[c], acc2,
                                                          0, 0, 0);
        }
        half4_t o4;
#pragma unroll
        for (int r = 0; r < 4; ++r) o4[r] = (_Float16)(acc2[r] * di2);
        if (onode < n)
            *(half4_t*)&out[(size_t)onode * F + t * 16 + quad * 4] = o4;
    }
}

// ---------------- final aggregation ----------------
// Best-known gather + pad-row indexing + v_fma_mix_f32 accumulate.

__global__ __launch_bounds__(256) void agg_to_f(const half8_t* __restrict__ h8,
                                                const float* __restrict__ dis,
                                                const float* __restrict__ bias,
                                                const int* __restrict__ srcs,
                                                const int* __restrict__ offs,
                                                float* __restrict__ out,
                                                int n, int E) {
    int node = blockIdx.x * 4 + (threadIdx.x >> 6);
    int lane = threadIdx.x & 63;
    if (node >= n) return;
    int g = lane >> 4;
    int fo = lane & 15;
    int beg = offs[node];
    int end = (node + 1 < n) ? offs[node + 1] : E;
    float di = dis[node];
    float one = 1.0f;
    half8_t hv = h8[(size_t)node * 16 + fo];
    float4 b0 = ((const float4*)bias)[fo * 2];
    float4 b1v = ((const float4*)bias)[fo * 2 + 1];
    float acc[8];
#pragma unroll
    for (int j = 0; j < 8; ++j) acc[j] = 0.f;
    if (beg < end) {
        int i0 = beg + g, i1 = beg + 4 + g;
        int s0 = (i0 < end) ? srcs[i0] : n;
        int s1 = (i1 < end) ? srcs[i1] : n;
        for (int e = beg; e < end; e += 8) {
            int ns0 = n, ns1 = n;
            if (e + 8 < end) {
                int j0 = e + 8 + g, j1 = e + 12 + g;
                ns0 = (j0 < end) ? srcs[j0] : n;
                ns1 = (j1 < end) ? srcs[j1] : n;
            }
            int4 a0 = *(const int4*)&h8[(size_t)s0 * 16 + fo];
            int4 a1 = *(const int4*)&h8[(size_t)s1 * 16 + fo];
            MIX_ROW(a0)
            MIX_ROW(a1)
            s0 = ns0; s1 = ns1;
        }
    }
#pragma unroll
    for (int j = 0; j < 8; ++j) {
        acc[j] += __shfl_xor(acc[j], 16);
        acc[j] += __shfl_xor(acc[j], 32);
    }
    if (lane >= 16) return;
    acc[0] = di * (acc[0] + (float)hv[0]) + b0.x;
    acc[1] = di * (acc[1] + (float)hv[1]) + b0.y;
    acc[2] = di * (acc[2] + (float)hv[2]) + b0.z;
    acc[3] = di * (acc[3] + (float)hv[3]) + b0.w;
    acc[4] = di * (acc[4] + (float)hv[4]) + b1v.x;
    acc[5] = di * (acc[5] + (float)hv[5]) + b1v.y;
    acc[6] = di * (acc[6] + (float)hv[6]) + b1v.z;
    acc[7] = di * (acc[7] + (float)hv[7]) + b1v.w;
#pragma unroll
    for (int j = 0; j < 8; ++j)
        acc[j] = (acc[j] > 0.f) ? acc[j] : acc[j] * NEG_SLOPE;
    float4 o0 = make_float4(acc[0], acc[1], acc[2], acc[3]);
    float4 o1 = make_float4(acc[4], acc[5], acc[6], acc[7]);
    ((float4*)out)[(size_t)node * 32 + fo * 2] = o0;
    ((float4*)out)[(size_t)node * 32 + fo * 2 + 1] = o1;
}

// ---------------- launch ----------------

static inline size_t alup(size_t x) { return (x + 255) & ~(size_t)255; }

extern "C" void kernel_launch(void* const* d_in, const int* in_sizes, int n_in,
                              void* d_out, int out_size, void* d_ws, size_t ws_size,
                              hipStream_t stream) {
    const float* x  = (const float*)d_in[0];
    const int*   ei = (const int*)d_in[1];
    const float* W1 = (const float*)d_in[2];
    const float* b1 = (const float*)d_in[3];
    const float* W2 = (const float*)d_in[4];
    const float* b2 = (const float*)d_in[5];
    float* out = (float*)d_out;

    const int N = in_sizes[0] / F;    // 100000  (< 2^17 for 4B packing)
    const int E = in_sizes[1] / 2;    // 1600000
    const int* src = ei;
    const int* dst = ei + E;

    char* p = (char*)d_ws;
    int*      bcnt   = (int*)p;      p += alup(PMAX * 4);
    int*      bbase  = (int*)p;      p += alup(PMAX * 4);
    int*      bcur   = (int*)p;      p += alup(PMAX * 4);
    float*    dis    = (float*)p;    p += alup((size_t)N * 4);
    int*      offs   = (int*)p;      p += alup((size_t)N * 4);
    int*      binned = (int*)p;      p += alup((size_t)E * 4);
    int*      srcs   = (int*)p;      p += alup((size_t)E * 4);
    _Float16* g      = (_Float16*)p; p += alup(((size_t)N + 1) * F * 2);  // +pad row
    _Float16* hh     = (_Float16*)p; p += alup(((size_t)N + 1) * F * 2);  // +pad row
    _Float16* W1h    = (_Float16*)p; p += alup((size_t)F * F * 2);
    _Float16* W2h    = (_Float16*)p; p += alup((size_t)F * F * 2);

    const int nP = (N + NPB - 1) / NPB;        // 196
    const int ntiles = (N + 15) / 16;          // 6250
    const int gemm_grid = (ntiles + 3) / 4;
    const int agg_grid = (N + 3) / 4;

    zero_bcnt<<<1, 512, 0, stream>>>(bcnt, bcur);
    hist_kernel<<<(E + HB - 1) / HB + 32, 256, 0, stream>>>(
        dst, bcnt, E, nP, W1, W2, W1h, W2h,
        hh + (size_t)N * F, g + (size_t)N * F);
    bin_kernel<<<(E + BB - 1) / BB, 256, 0, stream>>>(src, dst, bcnt, bcur,
                                                      bbase, binned, E, nP);
    csr_kernel<<<nP, 256, 0, stream>>>(binned, bcnt, bbase, srcs, offs, dis, N);

    // layer 1 GEMM: hh = (x @ W1.T)*dis (fp16)
    gemm_a32<<<gemm_grid, 256, 0, stream>>>(x, W1h, dis, hh, ntiles);
    // fused layer boundary: agg(hh)+b1+lrelu -> [LDS] -> @W2.T*dis -> g
    agg_gemm16<<<ntiles, 256, 0, stream>>>((const half8_t*)hh, dis, b1, W2h,
                                           srcs, offs, g, N, E);
    // layer 2 aggregation: agg(g)+b2+lrelu -> d_out (fp32)
    agg_to_f<<<agg_grid, 256, 0, stream>>>((const half8_t*)g, dis, b2, srcs,
                                           offs, out, N, E);
}

// Round 13
// 318.331 us; speedup vs baseline: 1.7433x; 1.0285x over previous
//
#include <hip/hip_runtime.h>

#define F 128
#define NEG_SLOPE 0.01f
#define NPB 512      // nodes per bucket (1<<9)
#define PMAX 256     // max buckets; nP = ceil(N/512) = 196
#define HB 8192      // edges per hist block
#define BB 8192      // edges per bin block
#define CAP 12288    // csr LDS staging capacity (avg 8192 + tail; key-0 << this)

typedef _Float16 half8_t __attribute__((ext_vector_type(8)));
typedef _Float16 half4_t __attribute__((ext_vector_type(4)));
typedef float f32x4 __attribute__((ext_vector_type(4)));

// ---------------- CSR build: two-level bucket sort (r5 structure) ----------------
// Edge records pack to 4B: (dst_local<<17)|src -- dst_local<512 (9b), src<2^17.

__global__ __launch_bounds__(512) void zero_bcnt(int* __restrict__ bcnt,
                                                 int* __restrict__ bcur) {
    int tid = threadIdx.x;
    if (tid < PMAX) bcnt[tid] = 0;
    else bcur[tid - PMAX] = 0;
}

// hist over dst buckets; last 32 blocks instead convert W1/W2 to fp16.
__global__ __launch_bounds__(256) void hist_kernel(const int* __restrict__ dst,
                                                   int* __restrict__ bcnt,
                                                   int E, int nP,
                                                   const float* __restrict__ W1,
                                                   const float* __restrict__ W2,
                                                   _Float16* __restrict__ W1h,
                                                   _Float16* __restrict__ W2h) {
    __shared__ int h[PMAX];
    int tid = threadIdx.x;
    int hb = gridDim.x - 32;
    if (blockIdx.x >= hb) {
        int i = (blockIdx.x - hb) * 256 + tid;    // 0 .. 8191 (2 * 128*128/4)
        const int n4 = F * F / 4;
        const float* in = (i < n4) ? W1 : W2;
        _Float16* out = (i < n4) ? W1h : W2h;
        int j = (i < n4) ? i : i - n4;
        float4 v = ((const float4*)in)[j];
        half8_t hx;  // only low 4 used
        hx[0] = (_Float16)v.x; hx[1] = (_Float16)v.y;
        hx[2] = (_Float16)v.z; hx[3] = (_Float16)v.w;
        *(int2*)&((_Float16*)out)[j * 4] = *(int2*)&hx;
        return;
    }
    if (tid < PMAX) h[tid] = 0;
    __syncthreads();
    int base = blockIdx.x * HB;
    for (int i = tid; i < HB && base + i < E; i += 256)
        atomicAdd(&h[dst[base + i] >> 9], 1);
    __syncthreads();
    if (tid < nP && h[tid]) atomicAdd(&bcnt[tid], h[tid]);
}

// bin: per-block bucket hist + local scan + in-block global scan of bcnt
// + LDS reorder + coalesced run writes.
__global__ __launch_bounds__(256) void bin_kernel(const int* __restrict__ src,
                                                  const int* __restrict__ dst,
                                                  const int* __restrict__ bcnt,
                                                  int* __restrict__ bcur,
                                                  int* __restrict__ bbase,
                                                  int* __restrict__ binned,
                                                  int E, int nP) {
    __shared__ int hist[PMAX];
    __shared__ int lbase[PMAX];
    __shared__ int gbase[PMAX];
    __shared__ int cur[PMAX];
    __shared__ int sa[PMAX];
    __shared__ int sb[PMAX];
    __shared__ int buf[BB];
    __shared__ unsigned char b8[BB];
    int tid = threadIdx.x;
    int base = blockIdx.x * BB;
    int myE = E - base; if (myE > BB) myE = BB;

    hist[tid] = 0;
    __syncthreads();
    for (int i = tid; i < myE; i += 256)
        atomicAdd(&hist[dst[base + i] >> 9], 1);
    __syncthreads();
    // scan A: local hist -> lbase/cur
    {
        int v = (tid < nP) ? hist[tid] : 0;
        int run = v;
        sa[tid] = v;
        __syncthreads();
        for (int off = 1; off < PMAX; off <<= 1) {
            int add = (tid >= off) ? sa[tid - off] : 0;
            __syncthreads();
            run += add;
            sa[tid] = run;
            __syncthreads();
        }
        if (tid < nP) { lbase[tid] = run - v; cur[tid] = run - v; }
    }
    // scan B: global bcnt -> exclusive prefix; alloc via bcur atomics
    {
        int v = (tid < nP) ? bcnt[tid] : 0;
        int run = v;
        sb[tid] = v;
        __syncthreads();
        for (int off = 1; off < PMAX; off <<= 1) {
            int add = (tid >= off) ? sb[tid - off] : 0;
            __syncthreads();
            run += add;
            sb[tid] = run;
            __syncthreads();
        }
        int gexc = run - v;
        if (tid < nP) {
            if (blockIdx.x == 0) bbase[tid] = gexc;
            gbase[tid] = hist[tid] ? gexc + atomicAdd(&bcur[tid], hist[tid]) : 0;
        }
    }
    __syncthreads();
    // reorder into LDS, bucket-contiguous
    for (int i = tid; i < myE; i += 256) {
        int d = dst[base + i], s = src[base + i];
        int b = d >> 9;
        int lp = atomicAdd(&cur[b], 1);
        buf[lp] = ((d & (NPB - 1)) << 17) | s;
        b8[lp] = (unsigned char)b;
    }
    __syncthreads();
    // coalesced run writes
    for (int j = tid; j < myE; j += 256) {
        int b = b8[j];
        binned[gbase[b] + (j - lbase[b])] = buf[j];
    }
}

// one block per bucket (196 blocks): exact CSR + offs + dis
__global__ __launch_bounds__(256) void csr_kernel(const int* __restrict__ binned,
                                                  const int* __restrict__ bcnt,
                                                  const int* __restrict__ bbase,
                                                  int* __restrict__ srcs,
                                                  int* __restrict__ offs,
                                                  float* __restrict__ dis, int N) {
    __shared__ int cnt[NPB];
    __shared__ int tmp[NPB];
    __shared__ int cur[NPB];
    __shared__ int buf[CAP];
    int tid = threadIdx.x;
    int b = blockIdx.x;
    int ebase = bbase[b];
    int count = bcnt[b];
    int lo = b << 9;
    cnt[tid] = 0;
    cnt[tid + 256] = 0;
    __syncthreads();
    for (int j = tid; j < count; j += 256)
        atomicAdd(&cnt[binned[ebase + j] >> 17], 1);
    __syncthreads();
    int j0 = tid, j1 = tid + 256;
    int v0 = cnt[j0], v1 = cnt[j1];
    tmp[j0] = v0; tmp[j1] = v1;
    __syncthreads();
    for (int off = 1; off < NPB; off <<= 1) {
        int t0 = tmp[j0] + (j0 >= off ? tmp[j0 - off] : 0);
        int t1 = tmp[j1] + (j1 >= off ? tmp[j1 - off] : 0);
        __syncthreads();
        tmp[j0] = t0; tmp[j1] = t1;
        __syncthreads();
    }
    int e0 = tmp[j0] - v0, e1 = tmp[j1] - v1;
    cur[j0] = e0; cur[j1] = e1;
    int n0 = lo + j0, n1 = lo + j1;
    if (n0 < N) { offs[n0] = ebase + e0; dis[n0] = rsqrtf((float)v0 + 1.0f); }
    if (n1 < N) { offs[n1] = ebase + e1; dis[n1] = rsqrtf((float)v1 + 1.0f); }
    __syncthreads();
    for (int j = tid; j < count; j += 256) {
        int rec = binned[ebase + j];
        int pos = atomicAdd(&cur[rec >> 17], 1);
        int s = rec & 0x1FFFF;
        if (pos < CAP) buf[pos] = s; else srcs[ebase + pos] = s;
    }
    __syncthreads();
    int lim = count < CAP ? count : CAP;
    for (int j = tid; j < lim; j += 256)
        srcs[ebase + j] = buf[j];
}

// ---------------- GEMM layer 1 (TRANSPOSED): hh = (x @ W1.T) * dis[row] ----------------
// mfma(A=W1-slice, B=x-nodes): D col=lane&15=node, row=quad*4+r=feature.
// Each lane writes 4 CONSECUTIVE features of one node per t-slice: 8 stores
// of 8B/lane instead of the old 32 scattered 2B stores (store-issue relief;
// loads are byte-identical to the untransposed version).

__global__ __launch_bounds__(256) void gemm_a32(const float* __restrict__ A,
                                                const _Float16* __restrict__ Wh,
                                                const float* __restrict__ dis,
                                                _Float16* __restrict__ out,
                                                int ntiles) {
    int wave = threadIdx.x >> 6;
    int lane = threadIdx.x & 63;
    int tile = blockIdx.x * 4 + wave;
    if (tile >= ntiles) return;
    int m = lane & 15, quad = lane >> 4;
    int node = tile * 16 + m;
    const float* arow = A + (size_t)node * F;
    half8_t xfrag[4];
#pragma unroll
    for (int c = 0; c < 4; ++c) {
        float4 t0 = *(const float4*)&arow[c * 32 + quad * 8];
        float4 t1 = *(const float4*)&arow[c * 32 + quad * 8 + 4];
        xfrag[c][0] = (_Float16)t0.x; xfrag[c][1] = (_Float16)t0.y;
        xfrag[c][2] = (_Float16)t0.z; xfrag[c][3] = (_Float16)t0.w;
        xfrag[c][4] = (_Float16)t1.x; xfrag[c][5] = (_Float16)t1.y;
        xfrag[c][6] = (_Float16)t1.z; xfrag[c][7] = (_Float16)t1.w;
    }
    float di = dis[node];
    _Float16* orow = out + (size_t)node * F;
#pragma unroll
    for (int t = 0; t < 8; ++t) {
        f32x4 acc = (f32x4){0.f, 0.f, 0.f, 0.f};
#pragma unroll
        for (int c = 0; c < 4; ++c) {
            half8_t wfrag = *(const half8_t*)&Wh[(t * 16 + m) * F + c * 32 + quad * 8];
            acc = __builtin_amdgcn_mfma_f32_16x16x32_f16(wfrag, xfrag[c], acc,
                                                         0, 0, 0);
        }
        half4_t o4;
#pragma unroll
        for (int r = 0; r < 4; ++r) o4[r] = (_Float16)(acc[r] * di);
        *(half4_t*)&orow[t * 16 + quad * 4] = o4;
    }
}

// ---------------- FUSED layer-boundary: agg(layer1) + GEMM(W2) ----------------
// r9 structure verbatim (best measured fused variant, 77.0us): 4 waves,
// XOR-swizzled LDS, transposed GEMM phase with 8B stores; plain masked
// gather (fma_mix asm reverted -- it fenced the scheduler, r12).

__global__ __launch_bounds__(256) void agg_gemm16(const half8_t* __restrict__ h8,
                                                  const float* __restrict__ dis,
                                                  const float* __restrict__ bias,
                                                  const _Float16* __restrict__ Wh,
                                                  const int* __restrict__ srcs,
                                                  const int* __restrict__ offs,
                                                  _Float16* __restrict__ out,
                                                  int n, int E) {
    __shared__ _Float16 Af[16 * F];   // 4KB, XOR-swizzled 16B chunks
    int tile = blockIdx.x;
    int w = threadIdx.x >> 6;         // 0..3
    int lane = threadIdx.x & 63;
    int g = lane >> 4;
    int fo = lane & 15;
    float4 b0 = ((const float4*)bias)[fo * 2];
    float4 b1v = ((const float4*)bias)[fo * 2 + 1];

#pragma unroll
    for (int i = 0; i < 4; ++i) {
        int row = w * 4 + i;
        int node = tile * 16 + row;
        float acc[8];
#pragma unroll
        for (int j = 0; j < 8; ++j) acc[j] = 0.f;
        int beg = 0, end = 0;
        float di = 0.f;
        half8_t hv = {};
        if (node < n) {
            beg = offs[node];
            end = (node + 1 < n) ? offs[node + 1] : E;
            di = dis[node];
            hv = h8[(size_t)node * 16 + fo];
        }
        if (beg < end) {
            int i0 = beg + g, i1 = beg + 4 + g;
            int s0 = srcs[i0 < end ? i0 : beg];
            int s1 = srcs[i1 < end ? i1 : beg];
            float w0 = (i0 < end) ? 1.f : 0.f;
            float w1 = (i1 < end) ? 1.f : 0.f;
            for (int e = beg; e < end; e += 8) {
                int ns0 = s0, ns1 = s1;
                float nw0 = 0.f, nw1 = 0.f;
                if (e + 8 < end) {
                    int j0 = e + 8 + g, j1 = e + 12 + g;
                    ns0 = srcs[j0 < end ? j0 : beg];
                    ns1 = srcs[j1 < end ? j1 : beg];
                    nw0 = (j0 < end) ? 1.f : 0.f;
                    nw1 = (j1 < end) ? 1.f : 0.f;
                }
                half8_t a0 = h8[(size_t)s0 * 16 + fo];
                half8_t a1 = h8[(size_t)s1 * 16 + fo];
#pragma unroll
                for (int j = 0; j < 8; ++j)
                    acc[j] += w0 * (float)a0[j] + w1 * (float)a1[j];
                s0 = ns0; s1 = ns1; w0 = nw0; w1 = nw1;
            }
        }
#pragma unroll
        for (int j = 0; j < 8; ++j) {
            acc[j] += __shfl_xor(acc[j], 16);
            acc[j] += __shfl_xor(acc[j], 32);
        }
        if (lane < 16) {
            half8_t o = {};
            if (node < n) {
                acc[0] = di * (acc[0] + (float)hv[0]) + b0.x;
                acc[1] = di * (acc[1] + (float)hv[1]) + b0.y;
                acc[2] = di * (acc[2] + (float)hv[2]) + b0.z;
                acc[3] = di * (acc[3] + (float)hv[3]) + b0.w;
                acc[4] = di * (acc[4] + (float)hv[4]) + b1v.x;
                acc[5] = di * (acc[5] + (float)hv[5]) + b1v.y;
                acc[6] = di * (acc[6] + (float)hv[6]) + b1v.z;
                acc[7] = di * (acc[7] + (float)hv[7]) + b1v.w;
#pragma unroll
                for (int j = 0; j < 8; ++j) {
                    float v = (acc[j] > 0.f) ? acc[j] : acc[j] * NEG_SLOPE;
                    o[j] = (_Float16)v;
                }
            }
            int cs = fo ^ (row & 7);                 // swizzled chunk
            *(half8_t*)&Af[row * F + cs * 8] = o;
        }
    }
    __syncthreads();

    // Transposed GEMM: A = W2 slice t (m=feature), B = Af (n=node).
    // D: col=lane&15=node, row=quad*4+r=feature-within-slice.
    int m = fo, quad = g;
    half8_t bfragA[4];
#pragma unroll
    for (int c = 0; c < 4; ++c)
        bfragA[c] = *(const half8_t*)&Af[fo * F + ((c * 4 + quad) ^ (fo & 7)) * 8];
    int onode = tile * 16 + fo;
    float di2 = (onode < n) ? dis[onode] : 0.f;
#pragma unroll
    for (int s = 0; s < 2; ++s) {
        int t = w * 2 + s;
        f32x4 acc2 = (f32x4){0.f, 0.f, 0.f, 0.f};
#pragma unroll
        for (int c = 0; c < 4; ++c) {
            half8_t afragW = *(const half8_t*)&Wh[(t * 16 + m) * F + c * 32 + quad * 8];
            acc2 = __builtin_amdgcn_mfma_f32_16x16x32_f16(afragW, bfragA[c], acc2,
                                                          0, 0, 0);
        }
        half4_t o4;
#pragma unroll
        for (int r = 0; r < 4; ++r) o4[r] = (_Float16)(acc2[r] * di2);
        if (onode < n)
            *(half4_t*)&out[(size_t)onode * F + t * 16 + quad * 4] = o4;
    }
}

// ---------------- final aggregation (r5/r8 plain best-known) ----------------

__global__ __launch_bounds__(256) void agg_to_f(const half8_t* __restrict__ h8,
                                                const float* __restrict__ dis,
                                                const float* __restrict__ bias,
                                                const int* __restrict__ srcs,
                                                const int* __restrict__ offs,
                                                float* __restrict__ out,
                                                int n, int E) {
    int node = blockIdx.x * 4 + (threadIdx.x >> 6);
    int lane = threadIdx.x & 63;
    if (node >= n) return;
    int g = lane >> 4;
    int fo = lane & 15;
    int beg = offs[node];
    int end = (node + 1 < n) ? offs[node + 1] : E;
    float di = dis[node];
    half8_t hv = h8[(size_t)node * 16 + fo];
    float4 b0 = ((const float4*)bias)[fo * 2];
    float4 b1v = ((const float4*)bias)[fo * 2 + 1];
    float acc[8];
#pragma unroll
    for (int j = 0; j < 8; ++j) acc[j] = 0.f;
    if (beg < end) {
        int i0 = beg + g, i1 = beg + 4 + g;
        int s0 = srcs[i0 < end ? i0 : beg];
        int s1 = srcs[i1 < end ? i1 : beg];
        float w0 = (i0 < end) ? 1.f : 0.f;
        float w1 = (i1 < end) ? 1.f : 0.f;
        for (int e = beg; e < end; e += 8) {
            int ns0 = s0, ns1 = s1;
            float nw0 = 0.f, nw1 = 0.f;
            if (e + 8 < end) {
                int j0 = e + 8 + g, j1 = e + 12 + g;
                ns0 = srcs[j0 < end ? j0 : beg];
                ns1 = srcs[j1 < end ? j1 : beg];
                nw0 = (j0 < end) ? 1.f : 0.f;
                nw1 = (j1 < end) ? 1.f : 0.f;
            }
            half8_t a0 = h8[(size_t)s0 * 16 + fo];
            half8_t a1 = h8[(size_t)s1 * 16 + fo];
#pragma unroll
            for (int j = 0; j < 8; ++j)
                acc[j] += w0 * (float)a0[j] + w1 * (float)a1[j];
            s0 = ns0; s1 = ns1; w0 = nw0; w1 = nw1;
        }
    }
#pragma unroll
    for (int j = 0; j < 8; ++j) {
        acc[j] += __shfl_xor(acc[j], 16);
        acc[j] += __shfl_xor(acc[j], 32);
    }
    if (lane >= 16) return;
    acc[0] = di * (acc[0] + (float)hv[0]) + b0.x;
    acc[1] = di * (acc[1] + (float)hv[1]) + b0.y;
    acc[2] = di * (acc[2] + (float)hv[2]) + b0.z;
    acc[3] = di * (acc[3] + (float)hv[3]) + b0.w;
    acc[4] = di * (acc[4] + (float)hv[4]) + b1v.x;
    acc[5] = di * (acc[5] + (float)hv[5]) + b1v.y;
    acc[6] = di * (acc[6] + (float)hv[6]) + b1v.z;
    acc[7] = di * (acc[7] + (float)hv[7]) + b1v.w;
#pragma unroll
    for (int j = 0; j < 8; ++j)
        acc[j] = (acc[j] > 0.f) ? acc[j] : acc[j] * NEG_SLOPE;
    float4 o0 = make_float4(acc[0], acc[1], acc[2], acc[3]);
    float4 o1 = make_float4(acc[4], acc[5], acc[6], acc[7]);
    ((float4*)out)[(size_t)node * 32 + fo * 2] = o0;
    ((float4*)out)[(size_t)node * 32 + fo * 2 + 1] = o1;
}

// ---------------- launch ----------------

static inline size_t alup(size_t x) { return (x + 255) & ~(size_t)255; }

extern "C" void kernel_launch(void* const* d_in, const int* in_sizes, int n_in,
                              void* d_out, int out_size, void* d_ws, size_t ws_size,
                              hipStream_t stream) {
    const float* x  = (const float*)d_in[0];
    const int*   ei = (const int*)d_in[1];
    const float* W1 = (const float*)d_in[2];
    const float* b1 = (const float*)d_in[3];
    const float* W2 = (const float*)d_in[4];
    const float* b2 = (const float*)d_in[5];
    float* out = (float*)d_out;

    const int N = in_sizes[0] / F;    // 100000  (< 2^17 for 4B packing)
    const int E = in_sizes[1] / 2;    // 1600000
    const int* src = ei;
    const int* dst = ei + E;

    char* p = (char*)d_ws;
    int*      bcnt   = (int*)p;      p += alup(PMAX * 4);
    int*      bbase  = (int*)p;      p += alup(PMAX * 4);
    int*      bcur   = (int*)p;      p += alup(PMAX * 4);
    float*    dis    = (float*)p;    p += alup((size_t)N * 4);
    int*      offs   = (int*)p;      p += alup((size_t)N * 4);
    int*      binned = (int*)p;      p += alup((size_t)E * 4);
    int*      srcs   = (int*)p;      p += alup((size_t)E * 4);
    _Float16* g      = (_Float16*)p; p += alup((size_t)N * F * 2);
    _Float16* hh     = (_Float16*)p; p += alup((size_t)N * F * 2);
    _Float16* W1h    = (_Float16*)p; p += alup((size_t)F * F * 2);
    _Float16* W2h    = (_Float16*)p; p += alup((size_t)F * F * 2);

    const int nP = (N + NPB - 1) / NPB;        // 196
    const int ntiles = (N + 15) / 16;          // 6250
    const int gemm_grid = (ntiles + 3) / 4;
    const int agg_grid = (N + 3) / 4;

    zero_bcnt<<<1, 512, 0, stream>>>(bcnt, bcur);
    hist_kernel<<<(E + HB - 1) / HB + 32, 256, 0, stream>>>(dst, bcnt, E, nP,
                                                            W1, W2, W1h, W2h);
    bin_kernel<<<(E + BB - 1) / BB, 256, 0, stream>>>(src, dst, bcnt, bcur,
                                                      bbase, binned, E, nP);
    csr_kernel<<<nP, 256, 0, stream>>>(binned, bcnt, bbase, srcs, offs, dis, N);

    // layer 1 GEMM (transposed stores): hh = (x @ W1.T)*dis (fp16)
    gemm_a32<<<gemm_grid, 256, 0, stream>>>(x, W1h, dis, hh, ntiles);
    // fused layer boundary: agg(hh)+b1+lrelu -> [LDS] -> @W2.T*dis -> g
    agg_gemm16<<<ntiles, 256, 0, stream>>>((const half8_t*)hh, dis, b1, W2h,
                                           srcs, offs, g, N, E);
    // layer 2 aggregation: agg(g)+b2+lrelu -> d_out (fp32)
    agg_to_f<<<agg_grid, 256, 0, stream>>>((const half8_t*)g, dis, b2, srcs,
                                           offs, out, N, E);
}